// Round 7
// baseline (812.622 us; speedup 1.0000x reference)
//
#include <hip/hip_runtime.h>
#include <hip/hip_cooperative_groups.h>

namespace cg = cooperative_groups;

#define N_NODES 100000
#define EMB 64
#define N_EDGES 1280000
#define N_E4 (N_EDGES / 4)      // 320000 int4 groups

#define NBUCK 196               // buckets of 512 nodes: dst >> 9
#define BUCK_SHIFT 9
#define BUCK_NODES 512

#define GB 1024                 // cooperative grid blocks
#define GT 256                  // threads per block
#define EPB4 ((N_E4 + GB - 1) / GB)   // 313 int4 groups per block
#define HTOT (NBUCK * GB)       // 200704 hist entries
#define PER (HTOT / GB)         // 196 scan entries per block (exact)

typedef unsigned long long u64;
typedef _Float16 f16;
typedef __attribute__((ext_vector_type(2))) _Float16 f16x2;

// ================= ONE cooperative kernel: entire CSR build + y0 =================
// Phases (grid.sync between): H bucket-hist -> S1 chunk scan -> S2 top scan ->
// SCAT packed scatter -> BUILD (rank+row_start+norm+col fill) -> Y0.
// Zero global atomics anywhere; LDS atomics only.
__global__ void __launch_bounds__(GT, 4) build_kernel(
    const int* __restrict__ src, const int* __restrict__ dst,
    const float* __restrict__ emb,
    int* __restrict__ hist, int* __restrict__ bsum,
    int* __restrict__ bedge, int* __restrict__ col,
    int* __restrict__ row_start, float* __restrict__ dinv,
    float* __restrict__ rdinv, f16* __restrict__ y0)
{
    cg::grid_group grid = cg::this_grid();
    const int b = blockIdx.x;
    const int tid = threadIdx.x;
    __shared__ int lh[BUCK_NODES];    // hist bins / per-node counts
    __shared__ int sc[GT];            // scan scratch
    __shared__ int cur[BUCK_NODES];   // cursors

    const int qbeg = b * EPB4;
    const int qend = (qbeg + EPB4 < N_E4) ? qbeg + EPB4 : N_E4;

    // ---- H: per-block bucket histogram (LDS atomics) ----
    for (int i = tid; i < NBUCK; i += GT) lh[i] = 0;
    __syncthreads();
    for (int q = qbeg + tid; q < qend; q += GT) {
        int4 d4 = ((const int4*)dst)[q];
        atomicAdd(&lh[d4.x >> BUCK_SHIFT], 1);
        atomicAdd(&lh[d4.y >> BUCK_SHIFT], 1);
        atomicAdd(&lh[d4.z >> BUCK_SHIFT], 1);
        atomicAdd(&lh[d4.w >> BUCK_SHIFT], 1);
    }
    __syncthreads();
    for (int i = tid; i < NBUCK; i += GT) hist[i * GB + b] = lh[i];  // bucket-major
    grid.sync();

    // ---- S1: each block scans its exact 196-entry chunk; emits chunk total ----
    {
        int idx = b * PER + tid;
        int v = (tid < PER) ? hist[idx] : 0;
        sc[tid] = v;
        __syncthreads();
        for (int off = 1; off < GT; off <<= 1) {
            int t = (tid >= off) ? sc[tid - off] : 0;
            __syncthreads();
            sc[tid] += t;
            __syncthreads();
        }
        if (tid < PER) hist[idx] = sc[tid] - v;     // chunk-exclusive
        if (tid == GT - 1) bsum[b] = sc[GT - 1];    // chunk total
    }
    grid.sync();

    // ---- S2: block 0 exclusive-scans the 1024 chunk totals ----
    if (b == 0) {
        int vals[4];
        int tsum = 0;
#pragma unroll
        for (int k = 0; k < 4; ++k) { vals[k] = bsum[tid * 4 + k]; tsum += vals[k]; }
        sc[tid] = tsum;
        __syncthreads();
        for (int off = 1; off < GT; off <<= 1) {
            int t = (tid >= off) ? sc[tid - off] : 0;
            __syncthreads();
            sc[tid] += t;
            __syncthreads();
        }
        int run = sc[tid] - tsum;
#pragma unroll
        for (int k = 0; k < 4; ++k) { int v = vals[k]; bsum[tid * 4 + k] = run; run += v; }
    }
    grid.sync();

    // ---- SCAT: scatter into ONE packed bucket-contiguous array.
    // packed = src | ((dst & 511) << 17): src < 2^17, local-dst 9 bits. ----
    for (int i = tid; i < NBUCK; i += GT) {
        int idx = i * GB + b;
        cur[i] = hist[idx] + bsum[idx / PER];
    }
    __syncthreads();
    for (int q = qbeg + tid; q < qend; q += GT) {
        int4 d4 = ((const int4*)dst)[q];
        int4 s4 = ((const int4*)src)[q];
        int p;
        p = atomicAdd(&cur[d4.x >> BUCK_SHIFT], 1);
        bedge[p] = s4.x | ((d4.x & (BUCK_NODES - 1)) << 17);
        p = atomicAdd(&cur[d4.y >> BUCK_SHIFT], 1);
        bedge[p] = s4.y | ((d4.y & (BUCK_NODES - 1)) << 17);
        p = atomicAdd(&cur[d4.z >> BUCK_SHIFT], 1);
        bedge[p] = s4.z | ((d4.z & (BUCK_NODES - 1)) << 17);
        p = atomicAdd(&cur[d4.w >> BUCK_SHIFT], 1);
        bedge[p] = s4.w | ((d4.w & (BUCK_NODES - 1)) << 17);
    }
    grid.sync();

    // ---- BUILD: one block per bucket: rank, row_start, norms, col fill ----
    if (b < NBUCK) {
        int i0 = b * GB;
        int beg = hist[i0] + bsum[i0 / PER];
        int end;
        if (b + 1 < NBUCK) {
            int i1 = (b + 1) * GB;
            end = hist[i1] + bsum[i1 / PER];
        } else {
            end = N_EDGES;
        }
        lh[tid] = 0;
        lh[tid + 256] = 0;
        __syncthreads();
        for (int i = beg + tid; i < end; i += GT)
            atomicAdd(&lh[((unsigned)bedge[i]) >> 17], 1);
        __syncthreads();
        int v0 = lh[2 * tid];
        int v1 = lh[2 * tid + 1];
        int tsum = v0 + v1;
        sc[tid] = tsum;
        __syncthreads();
        for (int off = 1; off < GT; off <<= 1) {
            int v = (tid >= off) ? sc[tid - off] : 0;
            __syncthreads();
            sc[tid] += v;
            __syncthreads();
        }
        int texcl = sc[tid] - tsum;
        cur[2 * tid] = texcl;
        cur[2 * tid + 1] = texcl + v0;
        __syncthreads();
        // row_start + norms (node==N_NODES cap falls out naturally in bucket 195)
        for (int i = tid; i < BUCK_NODES; i += GT) {
            int node = b * BUCK_NODES + i;
            if (node <= N_NODES) {
                row_start[node] = beg + cur[i];
                if (node < N_NODES) {
                    int d = lh[i];
                    float fd = (float)d;
                    dinv[node]  = (d > 0) ? rsqrtf(fd) : 0.0f;
                    rdinv[node] = (d > 0) ? sqrtf(fd) : 0.0f;
                }
            }
        }
        __syncthreads();   // row_start reads of cur[] complete before fill mutates it
        for (int i = beg + tid; i < end; i += GT) {
            unsigned pe = (unsigned)bedge[i];
            int r = atomicAdd(&cur[pe >> 17], 1);
            col[beg + r] = (int)(pe & 0x1FFFFu);
        }
    }
    grid.sync();

    // ---- Y0: full-grid y0 = dinv * emb -> fp16 (coalesced float4 -> u64) ----
    const int n4 = N_NODES * EMB / 4;
    for (int i = b * GT + tid; i < n4; i += GB * GT) {
        float dv = dinv[i >> 4];     // 16 float4s per 64-dim row
        float4 v = ((const float4*)emb)[i];
        f16 h[4] = {(f16)(v.x * dv), (f16)(v.y * dv), (f16)(v.z * dv), (f16)(v.w * dv)};
        ((u64*)y0)[i] = *(const u64*)h;
    }
}

// ---- propagation: one wave per destination row, two slots, 8-deep MLP ----
// (R3/R6-measured structure: 52 us FINAL, near the pull-model traffic minimum)
template <bool FINAL>
__global__ void gather_kernel(const int* __restrict__ row_start, const int* __restrict__ col,
                              const float* __restrict__ dinv, const float* __restrict__ rdinv,
                              const f16* __restrict__ yin, f16* __restrict__ yout,
                              const float* __restrict__ emb,
                              const f16* __restrict__ y1, const f16* __restrict__ y2,
                              float* __restrict__ out) {
    unsigned int gid = blockIdx.x * blockDim.x + threadIdx.x;
    unsigned int row = gid >> 6;       // wave-uniform
    int lane = (int)(gid & 63u);
    int s = lane >> 5;   // edge slot 0/1
    int j = lane & 31;   // dim pair: dims 2j, 2j+1
    if (row >= N_NODES) return;        // wave-uniform exit
    int beg = row_start[row];
    int end = row_start[row + 1];
    const f16* yj = yin + 2 * j;       // lane-fixed dim offset
    float accx = 0.0f, accy = 0.0f;
    for (int cb = beg; cb < end; cb += 64) {   // uniform bounds
        int idx = cb + lane;
        int ci = 0;
        if (idx < end) ci = col[idx];
        int n = end - cb;
        if (n > 64) n = 64;            // uniform
        int kk = 0;
        for (; kk + 8 <= n; kk += 8) { // 4 edges per slot: 8 gathers in flight/wave
            int c0 = __shfl(ci, kk + s);
            int c1 = __shfl(ci, kk + s + 2);
            int c2 = __shfl(ci, kk + s + 4);
            int c3 = __shfl(ci, kk + s + 6);
            unsigned u0 = *(const unsigned*)(yj + (unsigned)c0 * EMB);
            unsigned u1 = *(const unsigned*)(yj + (unsigned)c1 * EMB);
            unsigned u2 = *(const unsigned*)(yj + (unsigned)c2 * EMB);
            unsigned u3 = *(const unsigned*)(yj + (unsigned)c3 * EMB);
            f16x2 h0 = __builtin_bit_cast(f16x2, u0);
            f16x2 h1 = __builtin_bit_cast(f16x2, u1);
            f16x2 h2 = __builtin_bit_cast(f16x2, u2);
            f16x2 h3 = __builtin_bit_cast(f16x2, u3);
            accx += (float)h0.x + (float)h1.x + (float)h2.x + (float)h3.x;
            accy += (float)h0.y + (float)h1.y + (float)h2.y + (float)h3.y;
        }
        if (kk + 4 <= n) {             // uniform
            int c0 = __shfl(ci, kk + s);
            int c1 = __shfl(ci, kk + s + 2);
            unsigned u0 = *(const unsigned*)(yj + (unsigned)c0 * EMB);
            unsigned u1 = *(const unsigned*)(yj + (unsigned)c1 * EMB);
            f16x2 h0 = __builtin_bit_cast(f16x2, u0);
            f16x2 h1 = __builtin_bit_cast(f16x2, u1);
            accx += (float)h0.x + (float)h1.x;
            accy += (float)h0.y + (float)h1.y;
            kk += 4;
        }
        for (; kk < n; ++kk) {         // <=3 edges; shfl converged, acc predicated
            int c = __shfl(ci, kk);
            if (s == (kk & 1)) {
                unsigned u = *(const unsigned*)(yj + (unsigned)c * EMB);
                f16x2 h = __builtin_bit_cast(f16x2, u);
                accx += (float)h.x;
                accy += (float)h.y;
            }
        }
    }
    // merge the two edge slots (converged)
    accx += __shfl_xor(accx, 32);
    accy += __shfl_xor(accy, 32);
    if (s == 0) {
        float dv = dinv[row];
        unsigned int o = row * EMB + 2 * (unsigned)j;
        if (!FINAL) {
            float sc = dv * dv;
            f16x2 h;
            h.x = (f16)(accx * sc);
            h.y = (f16)(accy * sc);
            *(unsigned*)(yout + o) = __builtin_bit_cast(unsigned, h);  // cached: re-read next layer
        } else {
            float rv = rdinv[row];
            float2 e2 = *(const float2*)(emb + o);
            f16x2 a = __builtin_bit_cast(f16x2, *(const unsigned*)(y1 + o));
            f16x2 b = __builtin_bit_cast(f16x2, *(const unsigned*)(y2 + o));
            float rx = 0.25f * (e2.x + rv * ((float)a.x + (float)b.x) + dv * accx);
            float ry = 0.25f * (e2.y + rv * ((float)a.y + (float)b.y) + dv * accy);
            __builtin_nontemporal_store(rx, out + o);      // out is never re-read
            __builtin_nontemporal_store(ry, out + o + 1);
        }
    }
}

extern "C" void kernel_launch(void* const* d_in, const int* in_sizes, int n_in,
                              void* d_out, int out_size, void* d_ws, size_t ws_size,
                              hipStream_t stream) {
    const int*   edge = (const int*)d_in[0];   // (2, N_EDGES) row-major
    const int*   src  = (const int*)edge;
    const int*   dst  = (const int*)(edge + N_EDGES);
    const float* emb  = (const float*)d_in[1]; // (N_NODES, 64) fp32
    float*       out  = (float*)d_out;

    // workspace carve (16B-aligned offsets)
    char* ws = (char*)d_ws;
    size_t off = 0;
    int* row_start = (int*)(ws + off); off += 400016;
    int* bsum      = (int*)(ws + off); off += 4096;          // 1024 chunk sums
    float* dinv    = (float*)(ws + off); off += 400000;
    float* rdinv   = (float*)(ws + off); off += 400000;
    int* hist      = (int*)(ws + off); off += (size_t)HTOT * 4 + 16;        // 803 KB
    int* col       = (int*)(ws + off); off += (size_t)N_EDGES * 4;          // 5.12 MB
    f16* y0        = (f16*)(ws + off); off += (size_t)N_NODES * EMB * 2;    // 12.8 MB
    f16* y1        = (f16*)(ws + off); off += (size_t)N_NODES * EMB * 2;    // 12.8 MB
    f16* y2        = (f16*)(ws + off); off += (size_t)N_NODES * EMB * 2;    // 12.8 MB

    // packed edge array aliases y1: dead before layer-1 gather writes y1.
    int* bedge = (int*)y1;                       // 5.12 MB

    // ---- entire CSR build + y0: ONE cooperative dispatch ----
    void* args[] = { (void*)&src, (void*)&dst, (void*)&emb, (void*)&hist,
                     (void*)&bsum, (void*)&bedge, (void*)&col, (void*)&row_start,
                     (void*)&dinv, (void*)&rdinv, (void*)&y0 };
    hipLaunchCooperativeKernel((const void*)build_kernel, dim3(GB), dim3(GT),
                               args, 0, stream);

    // ---- 3 propagation layers (pure y-sums), final fuses the 1/4-sum ----
    const unsigned int gthreads = (unsigned int)N_NODES * EMB;
    const int gblocks = (int)((gthreads + 255) / 256);
    gather_kernel<false><<<gblocks, 256, 0, stream>>>(row_start, col, dinv, rdinv,
                                                      y0, y1, emb, y1, y2, out);
    gather_kernel<false><<<gblocks, 256, 0, stream>>>(row_start, col, dinv, rdinv,
                                                      y1, y2, emb, y1, y2, out);
    gather_kernel<true><<<gblocks, 256, 0, stream>>>(row_start, col, dinv, rdinv,
                                                     y2, (f16*)0, emb, y1, y2, out);
}

// Round 9
// 289.714 us; speedup vs baseline: 2.8049x; 2.8049x over previous
//
#include <hip/hip_runtime.h>

#define N_NODES 100000
#define EMB 64
#define N_EDGES 1280000
#define N_E4 (N_EDGES / 4)     // 320000 int4 groups

// counting-sort CSR build (no global atomics)
#define NBUCK 196               // buckets of 512 nodes: dst >> 9
#define BUCK_SHIFT 9
#define BUCK_NODES 512
#define NBA 313                 // ceil(N_EDGES / 4096)
#define HTOT (NBUCK * NBA)      // 61348 hist entries
#define NBH ((HTOT + 1023) / 1024)  // 60 hist-scan blocks

typedef unsigned long long u64;
typedef _Float16 f16;
typedef __attribute__((ext_vector_type(2))) _Float16 f16x2;
typedef __attribute__((ext_vector_type(4))) _Float16 f16x4;
typedef __attribute__((ext_vector_type(4))) float f32x4;   // nontemporal-store-safe

// ---- A1: per-block bucket histogram (LDS atomics only) ----
__global__ void bucket_hist_kernel(const int* __restrict__ dst, int* __restrict__ hist) {
    __shared__ int lh[NBUCK];
    for (int i = threadIdx.x; i < NBUCK; i += 256) lh[i] = 0;
    __syncthreads();
#pragma unroll
    for (int k = 0; k < 4; ++k) {
        int q = blockIdx.x * 1024 + k * 256 + threadIdx.x;  // int4 index, coalesced
        if (q < N_E4) {
            int4 d4 = ((const int4*)dst)[q];
            atomicAdd(&lh[d4.x >> BUCK_SHIFT], 1);
            atomicAdd(&lh[d4.y >> BUCK_SHIFT], 1);
            atomicAdd(&lh[d4.z >> BUCK_SHIFT], 1);
            atomicAdd(&lh[d4.w >> BUCK_SHIFT], 1);
        }
    }
    __syncthreads();
    for (int i = threadIdx.x; i < NBUCK; i += 256)
        hist[i * NBA + blockIdx.x] = lh[i];   // bucket-major layout for the scan
}

// ---- A2a: hierarchical scan pass 1 over hist (in-place) + block sums ----
__global__ void hist_scan1_kernel(int* __restrict__ hist, int* __restrict__ hbs) {
    __shared__ int lds[256];
    int base = blockIdx.x * 1024;
    int vals[4];
    int tsum = 0;
#pragma unroll
    for (int k = 0; k < 4; ++k) {
        int i = base + threadIdx.x * 4 + k;
        vals[k] = (i < HTOT) ? hist[i] : 0;
        tsum += vals[k];
    }
    lds[threadIdx.x] = tsum;
    __syncthreads();
    for (int off = 1; off < 256; off <<= 1) {
        int v = (threadIdx.x >= (unsigned)off) ? lds[threadIdx.x - off] : 0;
        __syncthreads();
        lds[threadIdx.x] += v;
        __syncthreads();
    }
    int run = lds[threadIdx.x] - tsum;      // local exclusive base
    if (threadIdx.x == 255) hbs[blockIdx.x] = lds[255];
    #pragma unroll
    for (int k = 0; k < 4; ++k) {
        int i = base + threadIdx.x * 4 + k;
        if (i < HTOT) hist[i] = run;        // in-place: own entries only
        run += vals[k];
    }
}

// ---- A2b: exclusive scan of the 60 hist block sums (tiny) ----
// Consumers (A3, B) add hbs[idx>>10] at read time -> no third pass.
__global__ void hist_scan2_kernel(int* __restrict__ hbs) {
    __shared__ int lds[64];
    int v = (threadIdx.x < (unsigned)NBH) ? hbs[threadIdx.x] : 0;
    lds[threadIdx.x] = v;
    __syncthreads();
    for (int off = 1; off < 64; off <<= 1) {
        int t = (threadIdx.x >= (unsigned)off) ? lds[threadIdx.x - off] : 0;
        __syncthreads();
        lds[threadIdx.x] += t;
        __syncthreads();
    }
    if (threadIdx.x < (unsigned)NBH) hbs[threadIdx.x] = lds[threadIdx.x] - v;
}

// ---- A3: scatter edges into ONE bucket-contiguous packed array.
// packed = src | ((dst & 511) << 17): src < 2^17, local-dst 9 bits. ----
__global__ void bucket_scatter_kernel(const int* __restrict__ src, const int* __restrict__ dst,
                                      const int* __restrict__ hist, const int* __restrict__ hbs,
                                      int* __restrict__ bedge) {
    __shared__ int cur[NBUCK];
    for (int i = threadIdx.x; i < NBUCK; i += 256) {
        int idx = i * NBA + blockIdx.x;
        cur[i] = hist[idx] + hbs[idx >> 10];
    }
    __syncthreads();
#pragma unroll
    for (int k = 0; k < 4; ++k) {
        int q = blockIdx.x * 1024 + k * 256 + threadIdx.x;
        if (q < N_E4) {
            int4 d4 = ((const int4*)dst)[q];
            int4 s4 = ((const int4*)src)[q];
            int p;
            p = atomicAdd(&cur[d4.x >> BUCK_SHIFT], 1);
            bedge[p] = s4.x | ((d4.x & (BUCK_NODES - 1)) << 17);
            p = atomicAdd(&cur[d4.y >> BUCK_SHIFT], 1);
            bedge[p] = s4.y | ((d4.y & (BUCK_NODES - 1)) << 17);
            p = atomicAdd(&cur[d4.z >> BUCK_SHIFT], 1);
            bedge[p] = s4.z | ((d4.z & (BUCK_NODES - 1)) << 17);
            p = atomicAdd(&cur[d4.w >> BUCK_SHIFT], 1);
            bedge[p] = s4.w | ((d4.w & (BUCK_NODES - 1)) << 17);
        }
    }
}

// ---- B: fused rank + row_start + norm + CSR fill + y0 (one block per bucket).
// Bucket b owns nodes [512b, 512b+512): deg sits in LDS, so dinv/rdinv/y0 for
// those nodes are produced locally with no global round-trip. ----
__global__ void bucket_build_kernel(const int* __restrict__ hist, const int* __restrict__ hbs,
                                    const int* __restrict__ bedge, const float* __restrict__ emb,
                                    int* __restrict__ col, int* __restrict__ row_start,
                                    float* __restrict__ dinv, float* __restrict__ rdinv,
                                    f16* __restrict__ y0) {
    __shared__ int lh[BUCK_NODES];
    __shared__ int sc[256];
    __shared__ int cur[BUCK_NODES];
    int k = blockIdx.x;
    int tid = threadIdx.x;
    int i0 = k * NBA;
    int beg = hist[i0] + hbs[i0 >> 10];
    int end;
    if (k + 1 < NBUCK) {
        int i1 = (k + 1) * NBA;
        end = hist[i1] + hbs[i1 >> 10];
    } else {
        end = N_EDGES;
    }
    lh[tid] = 0;
    lh[tid + 256] = 0;
    __syncthreads();
    // pass 1: per-node counts
    for (int i = beg + tid; i < end; i += 256)
        atomicAdd(&lh[((unsigned)bedge[i]) >> 17], 1);
    __syncthreads();
    // exclusive scan of 512 bins (2 per thread)
    int v0 = lh[2 * tid];
    int v1 = lh[2 * tid + 1];
    int tsum = v0 + v1;
    sc[tid] = tsum;
    __syncthreads();
    for (int off = 1; off < 256; off <<= 1) {
        int v = (tid >= off) ? sc[tid - off] : 0;
        __syncthreads();
        sc[tid] += v;
        __syncthreads();
    }
    int texcl = sc[tid] - tsum;
    cur[2 * tid] = texcl;
    cur[2 * tid + 1] = texcl + v0;
    __syncthreads();
    // row_start + norms (node==N_NODES cap falls out naturally in bucket 195)
    for (int i = tid; i < BUCK_NODES; i += 256) {
        int node = k * BUCK_NODES + i;
        if (node <= N_NODES) {
            row_start[node] = beg + cur[i];
            if (node < N_NODES) {
                int d = lh[i];
                float fd = (float)d;
                dinv[node]  = (d > 0) ? rsqrtf(fd) : 0.0f;
                rdinv[node] = (d > 0) ? sqrtf(fd) : 0.0f;
            }
        }
    }
    __syncthreads();   // row_start reads of cur[] complete before fill mutates it
    // pass 2: fill col (bucket-local window -> L2-resident)
    for (int i = beg + tid; i < end; i += 256) {
        unsigned pe = (unsigned)bedge[i];
        int r = atomicAdd(&cur[pe >> 17], 1);
        col[beg + r] = (int)(pe & 0x1FFFFu);
    }
    // y0 for this bucket's 512 nodes: dv recomputed from lh (not mutated after pass 1)
    int nbase = k * BUCK_NODES;
    for (int i = tid; i < BUCK_NODES * 16; i += 256) {
        int node = nbase + (i >> 4);
        if (node < N_NODES) {
            float dd = (float)lh[i >> 4];
            float dv = (dd > 0.0f) ? rsqrtf(dd) : 0.0f;
            int quad = i & 15;
            float4 v = ((const float4*)emb)[(size_t)node * 16 + quad];
            f16 h[4] = {(f16)(v.x * dv), (f16)(v.y * dv), (f16)(v.z * dv), (f16)(v.w * dv)};
            ((u64*)y0)[(size_t)node * 16 + quad] = *(const u64*)h;
        }
    }
}

// ---- propagation: one wave per destination row, 4 slots x 16 dim-quads ----
// Each load instruction fetches 4 rows (64 lanes x 8 B); the unrolled predicated
// issue loop puts ALL ~deg gathers in flight at once (vs 8-4-1 staging before).
// shfl executed unconditionally by all lanes (exec-uniform); load+acc predicated.
template <bool FINAL>
__global__ void gather_kernel(const int* __restrict__ row_start, const int* __restrict__ col,
                              const float* __restrict__ dinv, const float* __restrict__ rdinv,
                              const f16* __restrict__ yin, f16* __restrict__ yout,
                              const float* __restrict__ emb,
                              const f16* __restrict__ y1, const f16* __restrict__ y2,
                              float* __restrict__ out) {
    unsigned int gid = blockIdx.x * blockDim.x + threadIdx.x;
    unsigned int row = gid >> 6;       // wave-uniform
    int lane = (int)(gid & 63u);
    int s = lane >> 4;   // edge slot 0..3
    int j = lane & 15;   // dim quad: dims 4j..4j+3
    if (row >= N_NODES) return;        // wave-uniform (grid is exact anyway)
    int beg = row_start[row];
    int end = row_start[row + 1];
    const f16* yj = yin + 4 * j;       // lane-fixed dim offset
    float a0 = 0.0f, a1 = 0.0f, a2 = 0.0f, a3 = 0.0f;
    for (int cb = beg; cb < end; cb += 64) {   // uniform bounds (runs once for deg<=64)
        int idx = cb + lane;
        int ci = 0;
        if (idx < end) ci = col[idx];
        int n = end - cb;
        if (n > 64) n = 64;            // uniform
#pragma unroll
        for (int kk = 0; kk < 16; ++kk) {
            int e = 4 * kk + s;                 // slot s covers edges e == s (mod 4)
            int c = __shfl(ci, e);              // all lanes execute (exec-uniform)
            if (e < n) {                        // load+acc exec-masked
                u64 u = *(const u64*)(yj + (unsigned)c * EMB);
                f16x4 h = __builtin_bit_cast(f16x4, u);
                a0 += (float)h.x;
                a1 += (float)h.y;
                a2 += (float)h.z;
                a3 += (float)h.w;
            }
        }
    }
    // reduce across the 4 edge slots (converged)
    a0 += __shfl_xor(a0, 16); a1 += __shfl_xor(a1, 16);
    a2 += __shfl_xor(a2, 16); a3 += __shfl_xor(a3, 16);
    a0 += __shfl_xor(a0, 32); a1 += __shfl_xor(a1, 32);
    a2 += __shfl_xor(a2, 32); a3 += __shfl_xor(a3, 32);
    if (s == 0) {                       // lanes 0..15 write 8 B (or 16 B) each
        float dv = dinv[row];
        unsigned int o = row * EMB + 4 * (unsigned)j;
        if (!FINAL) {
            float sc = dv * dv;
            f16 h[4] = {(f16)(a0 * sc), (f16)(a1 * sc), (f16)(a2 * sc), (f16)(a3 * sc)};
            *(u64*)(yout + o) = *(const u64*)h;   // cached: re-read next layer
        } else {
            float rv = rdinv[row];
            float4 e2 = *(const float4*)(emb + o);
            f16x4 a = __builtin_bit_cast(f16x4, *(const u64*)(y1 + o));
            f16x4 b = __builtin_bit_cast(f16x4, *(const u64*)(y2 + o));
            f32x4 r;
            r.x = 0.25f * (e2.x + rv * ((float)a.x + (float)b.x) + dv * a0);
            r.y = 0.25f * (e2.y + rv * ((float)a.y + (float)b.y) + dv * a1);
            r.z = 0.25f * (e2.z + rv * ((float)a.z + (float)b.z) + dv * a2);
            r.w = 0.25f * (e2.w + rv * ((float)a.w + (float)b.w) + dv * a3);
            __builtin_nontemporal_store(r, (f32x4*)(out + o));  // out is never re-read
        }
    }
}

extern "C" void kernel_launch(void* const* d_in, const int* in_sizes, int n_in,
                              void* d_out, int out_size, void* d_ws, size_t ws_size,
                              hipStream_t stream) {
    const int*   edge = (const int*)d_in[0];   // (2, N_EDGES) row-major
    const int*   src  = edge;
    const int*   dst  = edge + N_EDGES;
    const float* emb  = (const float*)d_in[1]; // (N_NODES, 64) fp32
    float*       out  = (float*)d_out;

    // workspace carve (16B-aligned offsets)
    char* ws = (char*)d_ws;
    size_t off = 0;
    int* row_start = (int*)(ws + off); off += 400016;
    int* hbs       = (int*)(ws + off); off += 256;   // hist-scan block sums (60)
    float* dinv    = (float*)(ws + off); off += 400000;
    float* rdinv   = (float*)(ws + off); off += 400000;
    int* hist      = (int*)(ws + off); off += (size_t)HTOT * 4 + 16;        // 245 KB
    int* col       = (int*)(ws + off); off += (size_t)N_EDGES * 4;          // 5.12 MB
    f16* y0        = (f16*)(ws + off); off += (size_t)N_NODES * EMB * 2;    // 12.8 MB
    f16* y1        = (f16*)(ws + off); off += (size_t)N_NODES * EMB * 2;    // 12.8 MB
    f16* y2        = (f16*)(ws + off); off += (size_t)N_NODES * EMB * 2;    // 12.8 MB

    // packed edge array aliases y1: dead before layer-1 gather writes y1.
    int* bedge = (int*)y1;                       // 5.12 MB

    // ---- CSR build via bucketed counting sort: zero global atomics, 5 dispatches ----
    bucket_hist_kernel<<<NBA, 256, 0, stream>>>(dst, hist);
    hist_scan1_kernel<<<NBH, 256, 0, stream>>>(hist, hbs);
    hist_scan2_kernel<<<1, 64, 0, stream>>>(hbs);
    bucket_scatter_kernel<<<NBA, 256, 0, stream>>>(src, dst, hist, hbs, bedge);
    bucket_build_kernel<<<NBUCK, 256, 0, stream>>>(hist, hbs, bedge, emb, col,
                                                   row_start, dinv, rdinv, y0);

    // ---- 3 propagation layers (pure y-sums), final fuses the 1/4-sum ----
    const unsigned int gthreads = (unsigned int)N_NODES * EMB;
    const int gblocks = (int)((gthreads + 255) / 256);
    gather_kernel<false><<<gblocks, 256, 0, stream>>>(row_start, col, dinv, rdinv,
                                                      y0, y1, emb, y1, y2, out);
    gather_kernel<false><<<gblocks, 256, 0, stream>>>(row_start, col, dinv, rdinv,
                                                      y1, y2, emb, y1, y2, out);
    gather_kernel<true><<<gblocks, 256, 0, stream>>>(row_start, col, dinv, rdinv,
                                                     y2, (f16*)0, emb, y1, y2, out);
}

// Round 10
// 261.602 us; speedup vs baseline: 3.1063x; 1.1075x over previous
//
#include <hip/hip_runtime.h>

#define N_NODES 100000
#define EMB 64
#define N_EDGES 1280000
#define N_E4 (N_EDGES / 4)     // 320000 int4 groups

// counting-sort CSR build (no global atomics)
#define NBUCK 196               // buckets of 512 nodes: dst >> 9
#define BUCK_SHIFT 9
#define BUCK_NODES 512
#define NBA 313                 // ceil(N_EDGES / 4096)
#define HTOT (NBUCK * NBA)      // 61348 hist entries
#define NBH ((HTOT + 1023) / 1024)  // 60 hist-scan blocks
#define EPB 4096                // edges staged per scatter block

typedef unsigned long long u64;
typedef _Float16 f16;
typedef __attribute__((ext_vector_type(2))) _Float16 f16x2;

// ---- A1: per-block bucket histogram (LDS atomics only) ----
__global__ void bucket_hist_kernel(const int* __restrict__ dst, int* __restrict__ hist) {
    __shared__ int lh[NBUCK];
    for (int i = threadIdx.x; i < NBUCK; i += 256) lh[i] = 0;
    __syncthreads();
#pragma unroll
    for (int k = 0; k < 4; ++k) {
        int q = blockIdx.x * 1024 + k * 256 + threadIdx.x;  // int4 index, coalesced
        if (q < N_E4) {
            int4 d4 = ((const int4*)dst)[q];
            atomicAdd(&lh[d4.x >> BUCK_SHIFT], 1);
            atomicAdd(&lh[d4.y >> BUCK_SHIFT], 1);
            atomicAdd(&lh[d4.z >> BUCK_SHIFT], 1);
            atomicAdd(&lh[d4.w >> BUCK_SHIFT], 1);
        }
    }
    __syncthreads();
    for (int i = threadIdx.x; i < NBUCK; i += 256)
        hist[i * NBA + blockIdx.x] = lh[i];   // bucket-major layout for the scan
}

// ---- A2a: hierarchical scan pass 1 over hist (in-place) + block sums ----
__global__ void hist_scan1_kernel(int* __restrict__ hist, int* __restrict__ hbs) {
    __shared__ int lds[256];
    int base = blockIdx.x * 1024;
    int vals[4];
    int tsum = 0;
#pragma unroll
    for (int k = 0; k < 4; ++k) {
        int i = base + threadIdx.x * 4 + k;
        vals[k] = (i < HTOT) ? hist[i] : 0;
        tsum += vals[k];
    }
    lds[threadIdx.x] = tsum;
    __syncthreads();
    for (int off = 1; off < 256; off <<= 1) {
        int v = (threadIdx.x >= (unsigned)off) ? lds[threadIdx.x - off] : 0;
        __syncthreads();
        lds[threadIdx.x] += v;
        __syncthreads();
    }
    int run = lds[threadIdx.x] - tsum;      // local exclusive base
    if (threadIdx.x == 255) hbs[blockIdx.x] = lds[255];
    #pragma unroll
    for (int k = 0; k < 4; ++k) {
        int i = base + threadIdx.x * 4 + k;
        if (i < HTOT) hist[i] = run;        // in-place: own entries only
        run += vals[k];
    }
}

// ---- A2b: exclusive scan of the 60 hist block sums (tiny) ----
// Consumers (A3, B) add hbs[idx>>10] at read time -> no third pass.
__global__ void hist_scan2_kernel(int* __restrict__ hbs) {
    __shared__ int lds[64];
    int v = (threadIdx.x < (unsigned)NBH) ? hbs[threadIdx.x] : 0;
    lds[threadIdx.x] = v;
    __syncthreads();
    for (int off = 1; off < 64; off <<= 1) {
        int t = (threadIdx.x >= (unsigned)off) ? lds[threadIdx.x - off] : 0;
        __syncthreads();
        lds[threadIdx.x] += t;
        __syncthreads();
    }
    if (threadIdx.x < (unsigned)NBH) hbs[threadIdx.x] = lds[threadIdx.x] - v;
}

// ---- A3: SORTED scatter. Block stages its 4096 edges in LDS grouped by bucket,
// then streams them out in bucket order -> writes are contiguous runs (~21 edges)
// at deterministic bases hist[i*NBA+b], zero global atomics.
// packed = src | ((dst & 511) << 17): src < 2^17, local-dst 9 bits. ----
__global__ void bucket_scatter_kernel(const int* __restrict__ src, const int* __restrict__ dst,
                                      const int* __restrict__ hist, const int* __restrict__ hbs,
                                      int* __restrict__ bedge) {
    __shared__ unsigned      sedge[EPB];     // 16 KB staged packed edges
    __shared__ unsigned char sbk[EPB];       // 4 KB bucket id per slot
    __shared__ int cnt[NBUCK];               // counts -> cursor
    __shared__ int loff[NBUCK];              // local exclusive offsets
    __shared__ int gbase[NBUCK];             // global base per bucket for this block
    __shared__ int ssc[256];
    const int b = blockIdx.x;
    const int tid = threadIdx.x;

    for (int i = tid; i < NBUCK; i += 256) cnt[i] = 0;
    __syncthreads();

    // load 16 edges/thread, keep in registers, count buckets
    unsigned pk[16];
    int bk[16];
#pragma unroll
    for (int k = 0; k < 4; ++k) {
        int q = b * 1024 + k * 256 + tid;
        if (q < N_E4) {
            int4 d4 = ((const int4*)dst)[q];
            int4 s4 = ((const int4*)src)[q];
            pk[4*k+0] = (unsigned)(s4.x | ((d4.x & (BUCK_NODES - 1)) << 17));
            pk[4*k+1] = (unsigned)(s4.y | ((d4.y & (BUCK_NODES - 1)) << 17));
            pk[4*k+2] = (unsigned)(s4.z | ((d4.z & (BUCK_NODES - 1)) << 17));
            pk[4*k+3] = (unsigned)(s4.w | ((d4.w & (BUCK_NODES - 1)) << 17));
            bk[4*k+0] = d4.x >> BUCK_SHIFT;
            bk[4*k+1] = d4.y >> BUCK_SHIFT;
            bk[4*k+2] = d4.z >> BUCK_SHIFT;
            bk[4*k+3] = d4.w >> BUCK_SHIFT;
            atomicAdd(&cnt[bk[4*k+0]], 1);
            atomicAdd(&cnt[bk[4*k+1]], 1);
            atomicAdd(&cnt[bk[4*k+2]], 1);
            atomicAdd(&cnt[bk[4*k+3]], 1);
        } else {
            bk[4*k+0] = -1; bk[4*k+1] = -1; bk[4*k+2] = -1; bk[4*k+3] = -1;
        }
    }
    __syncthreads();

    // exclusive scan of the 196 counts (256-entry scan, zeros above NBUCK)
    int own = (tid < NBUCK) ? cnt[tid] : 0;
    ssc[tid] = own;
    __syncthreads();
    for (int off = 1; off < 256; off <<= 1) {
        int v = (tid >= off) ? ssc[tid - off] : 0;
        __syncthreads();
        ssc[tid] += v;
        __syncthreads();
    }
    if (tid < NBUCK) {
        int excl = ssc[tid] - own;
        loff[tid] = excl;
        cnt[tid] = excl;                      // reuse as placement cursor
        int idx = tid * NBA + b;
        gbase[tid] = hist[idx] + hbs[idx >> 10];
    }
    __syncthreads();

    // place into LDS grouped by bucket
#pragma unroll
    for (int e = 0; e < 16; ++e) {
        if (bk[e] >= 0) {
            int slot = atomicAdd(&cnt[bk[e]], 1);
            sedge[slot] = pk[e];
            sbk[slot] = (unsigned char)bk[e];
        }
    }
    __syncthreads();

    // stream out: consecutive t -> consecutive addresses within each bucket run
    int ne = (b * 1024 + 1024 <= N_E4) ? EPB : (N_E4 - b * 1024) * 4;
    for (int t = tid; t < ne; t += 256) {
        int kb = sbk[t];
        bedge[gbase[kb] + (t - loff[kb])] = (int)sedge[t];
    }
}

// ---- B: fused rank + row_start + norm + CSR fill + y0 (one block per bucket).
// Bucket b owns nodes [512b, 512b+512): deg sits in LDS, so dinv/rdinv/y0 for
// those nodes are produced locally with no global round-trip. ----
__global__ void bucket_build_kernel(const int* __restrict__ hist, const int* __restrict__ hbs,
                                    const int* __restrict__ bedge, const float* __restrict__ emb,
                                    int* __restrict__ col, int* __restrict__ row_start,
                                    float* __restrict__ dinv, float* __restrict__ rdinv,
                                    f16* __restrict__ y0) {
    __shared__ int lh[BUCK_NODES];
    __shared__ int sc[256];
    __shared__ int cur[BUCK_NODES];
    int k = blockIdx.x;
    int tid = threadIdx.x;
    int i0 = k * NBA;
    int beg = hist[i0] + hbs[i0 >> 10];
    int end;
    if (k + 1 < NBUCK) {
        int i1 = (k + 1) * NBA;
        end = hist[i1] + hbs[i1 >> 10];
    } else {
        end = N_EDGES;
    }
    lh[tid] = 0;
    lh[tid + 256] = 0;
    __syncthreads();
    // pass 1: per-node counts
    for (int i = beg + tid; i < end; i += 256)
        atomicAdd(&lh[((unsigned)bedge[i]) >> 17], 1);
    __syncthreads();
    // exclusive scan of 512 bins (2 per thread)
    int v0 = lh[2 * tid];
    int v1 = lh[2 * tid + 1];
    int tsum = v0 + v1;
    sc[tid] = tsum;
    __syncthreads();
    for (int off = 1; off < 256; off <<= 1) {
        int v = (tid >= off) ? sc[tid - off] : 0;
        __syncthreads();
        sc[tid] += v;
        __syncthreads();
    }
    int texcl = sc[tid] - tsum;
    cur[2 * tid] = texcl;
    cur[2 * tid + 1] = texcl + v0;
    __syncthreads();
    // row_start + norms (node==N_NODES cap falls out naturally in bucket 195)
    for (int i = tid; i < BUCK_NODES; i += 256) {
        int node = k * BUCK_NODES + i;
        if (node <= N_NODES) {
            row_start[node] = beg + cur[i];
            if (node < N_NODES) {
                int d = lh[i];
                float fd = (float)d;
                dinv[node]  = (d > 0) ? rsqrtf(fd) : 0.0f;
                rdinv[node] = (d > 0) ? sqrtf(fd) : 0.0f;
            }
        }
    }
    __syncthreads();   // row_start reads of cur[] complete before fill mutates it
    // pass 2: fill col (bucket-local window -> L2-resident)
    for (int i = beg + tid; i < end; i += 256) {
        unsigned pe = (unsigned)bedge[i];
        int r = atomicAdd(&cur[pe >> 17], 1);
        col[beg + r] = (int)(pe & 0x1FFFFu);
    }
    // y0 for this bucket's 512 nodes: dv recomputed from lh (not mutated after pass 1)
    int nbase = k * BUCK_NODES;
    for (int i = tid; i < BUCK_NODES * 16; i += 256) {
        int node = nbase + (i >> 4);
        if (node < N_NODES) {
            float dd = (float)lh[i >> 4];
            float dv = (dd > 0.0f) ? rsqrtf(dd) : 0.0f;
            int quad = i & 15;
            float4 v = ((const float4*)emb)[(size_t)node * 16 + quad];
            f16 h[4] = {(f16)(v.x * dv), (f16)(v.y * dv), (f16)(v.z * dv), (f16)(v.w * dv)};
            ((u64*)y0)[(size_t)node * 16 + quad] = *(const u64*)h;
        }
    }
}

// ---- propagation: one wave per destination row, two slots, 8-deep MLP ----
// (R3/R6-proven structure: 52 us FINAL. 8 independent loads issued before any
// consume is what buys the latency hiding -- R8's predicated unroll regressed.)
template <bool FINAL>
__global__ void gather_kernel(const int* __restrict__ row_start, const int* __restrict__ col,
                              const float* __restrict__ dinv, const float* __restrict__ rdinv,
                              const f16* __restrict__ yin, f16* __restrict__ yout,
                              const float* __restrict__ emb,
                              const f16* __restrict__ y1, const f16* __restrict__ y2,
                              float* __restrict__ out) {
    unsigned int gid = blockIdx.x * blockDim.x + threadIdx.x;
    unsigned int row = gid >> 6;       // wave-uniform
    int lane = (int)(gid & 63u);
    int s = lane >> 5;   // edge slot 0/1
    int j = lane & 31;   // dim pair: dims 2j, 2j+1
    if (row >= N_NODES) return;        // wave-uniform exit
    int beg = row_start[row];
    int end = row_start[row + 1];
    const f16* yj = yin + 2 * j;       // lane-fixed dim offset
    float accx = 0.0f, accy = 0.0f;
    for (int cb = beg; cb < end; cb += 64) {   // uniform bounds
        int idx = cb + lane;
        int ci = 0;
        if (idx < end) ci = col[idx];
        int n = end - cb;
        if (n > 64) n = 64;            // uniform
        int kk = 0;
        for (; kk + 8 <= n; kk += 8) { // 4 edges per slot: 8 gathers in flight/wave
            int c0 = __shfl(ci, kk + s);
            int c1 = __shfl(ci, kk + s + 2);
            int c2 = __shfl(ci, kk + s + 4);
            int c3 = __shfl(ci, kk + s + 6);
            unsigned u0 = *(const unsigned*)(yj + (unsigned)c0 * EMB);
            unsigned u1 = *(const unsigned*)(yj + (unsigned)c1 * EMB);
            unsigned u2 = *(const unsigned*)(yj + (unsigned)c2 * EMB);
            unsigned u3 = *(const unsigned*)(yj + (unsigned)c3 * EMB);
            f16x2 h0 = __builtin_bit_cast(f16x2, u0);
            f16x2 h1 = __builtin_bit_cast(f16x2, u1);
            f16x2 h2 = __builtin_bit_cast(f16x2, u2);
            f16x2 h3 = __builtin_bit_cast(f16x2, u3);
            accx += (float)h0.x + (float)h1.x + (float)h2.x + (float)h3.x;
            accy += (float)h0.y + (float)h1.y + (float)h2.y + (float)h3.y;
        }
        if (kk + 4 <= n) {             // uniform
            int c0 = __shfl(ci, kk + s);
            int c1 = __shfl(ci, kk + s + 2);
            unsigned u0 = *(const unsigned*)(yj + (unsigned)c0 * EMB);
            unsigned u1 = *(const unsigned*)(yj + (unsigned)c1 * EMB);
            f16x2 h0 = __builtin_bit_cast(f16x2, u0);
            f16x2 h1 = __builtin_bit_cast(f16x2, u1);
            accx += (float)h0.x + (float)h1.x;
            accy += (float)h0.y + (float)h1.y;
            kk += 4;
        }
        for (; kk < n; ++kk) {         // <=3 edges; shfl converged, acc predicated
            int c = __shfl(ci, kk);
            if (s == (kk & 1)) {
                unsigned u = *(const unsigned*)(yj + (unsigned)c * EMB);
                f16x2 h = __builtin_bit_cast(f16x2, u);
                accx += (float)h.x;
                accy += (float)h.y;
            }
        }
    }
    // merge the two edge slots (converged)
    accx += __shfl_xor(accx, 32);
    accy += __shfl_xor(accy, 32);
    if (s == 0) {
        float dv = dinv[row];
        unsigned int o = row * EMB + 2 * (unsigned)j;
        if (!FINAL) {
            float sc = dv * dv;
            f16x2 h;
            h.x = (f16)(accx * sc);
            h.y = (f16)(accy * sc);
            *(unsigned*)(yout + o) = __builtin_bit_cast(unsigned, h);  // cached: re-read next layer
        } else {
            float rv = rdinv[row];
            float2 e2 = *(const float2*)(emb + o);
            f16x2 a = __builtin_bit_cast(f16x2, *(const unsigned*)(y1 + o));
            f16x2 b = __builtin_bit_cast(f16x2, *(const unsigned*)(y2 + o));
            float rx = 0.25f * (e2.x + rv * ((float)a.x + (float)b.x) + dv * accx);
            float ry = 0.25f * (e2.y + rv * ((float)a.y + (float)b.y) + dv * accy);
            __builtin_nontemporal_store(rx, out + o);      // out is never re-read
            __builtin_nontemporal_store(ry, out + o + 1);
        }
    }
}

extern "C" void kernel_launch(void* const* d_in, const int* in_sizes, int n_in,
                              void* d_out, int out_size, void* d_ws, size_t ws_size,
                              hipStream_t stream) {
    const int*   edge = (const int*)d_in[0];   // (2, N_EDGES) row-major
    const int*   src  = edge;
    const int*   dst  = edge + N_EDGES;
    const float* emb  = (const float*)d_in[1]; // (N_NODES, 64) fp32
    float*       out  = (float*)d_out;

    // workspace carve (16B-aligned offsets)
    char* ws = (char*)d_ws;
    size_t off = 0;
    int* row_start = (int*)(ws + off); off += 400016;
    int* hbs       = (int*)(ws + off); off += 256;   // hist-scan block sums (60)
    float* dinv    = (float*)(ws + off); off += 400000;
    float* rdinv   = (float*)(ws + off); off += 400000;
    int* hist      = (int*)(ws + off); off += (size_t)HTOT * 4 + 16;        // 245 KB
    int* col       = (int*)(ws + off); off += (size_t)N_EDGES * 4;          // 5.12 MB
    f16* y0        = (f16*)(ws + off); off += (size_t)N_NODES * EMB * 2;    // 12.8 MB
    f16* y1        = (f16*)(ws + off); off += (size_t)N_NODES * EMB * 2;    // 12.8 MB
    f16* y2        = (f16*)(ws + off); off += (size_t)N_NODES * EMB * 2;    // 12.8 MB

    // packed edge array aliases y1: dead before layer-1 gather writes y1.
    int* bedge = (int*)y1;                       // 5.12 MB

    // ---- CSR build via bucketed counting sort: zero global atomics, 5 dispatches ----
    bucket_hist_kernel<<<NBA, 256, 0, stream>>>(dst, hist);
    hist_scan1_kernel<<<NBH, 256, 0, stream>>>(hist, hbs);
    hist_scan2_kernel<<<1, 64, 0, stream>>>(hbs);
    bucket_scatter_kernel<<<NBA, 256, 0, stream>>>(src, dst, hist, hbs, bedge);
    bucket_build_kernel<<<NBUCK, 256, 0, stream>>>(hist, hbs, bedge, emb, col,
                                                   row_start, dinv, rdinv, y0);

    // ---- 3 propagation layers (pure y-sums), final fuses the 1/4-sum ----
    const unsigned int gthreads = (unsigned int)N_NODES * EMB;
    const int gblocks = (int)((gthreads + 255) / 256);
    gather_kernel<false><<<gblocks, 256, 0, stream>>>(row_start, col, dinv, rdinv,
                                                      y0, y1, emb, y1, y2, out);
    gather_kernel<false><<<gblocks, 256, 0, stream>>>(row_start, col, dinv, rdinv,
                                                      y1, y2, emb, y1, y2, out);
    gather_kernel<true><<<gblocks, 256, 0, stream>>>(row_start, col, dinv, rdinv,
                                                     y2, (f16*)0, emb, y1, y2, out);
}

// Round 11
// 258.592 us; speedup vs baseline: 3.1425x; 1.0116x over previous
//
#include <hip/hip_runtime.h>

#define N_NODES 100000
#define EMB 64
#define N_EDGES 1280000
#define N_E4 (N_EDGES / 4)     // 320000 int4 groups

// counting-sort CSR build (no global atomics)
#define NBUCK 782               // buckets of 128 nodes: dst >> 7
#define BUCK_SHIFT 7
#define BUCK_NODES 128
#define NBA 313                 // ceil(N_EDGES / 4096) edge-blocks
#define HTOT (NBUCK * NBA)      // 244766 hist entries
#define NBH ((HTOT + 1023) / 1024)  // 240 hist-scan blocks

typedef unsigned long long u64;
typedef _Float16 f16;
typedef __attribute__((ext_vector_type(2))) _Float16 f16x2;

// ---- A1: per-block bucket histogram (LDS atomics only) ----
__global__ void bucket_hist_kernel(const int* __restrict__ dst, int* __restrict__ hist) {
    __shared__ int lh[NBUCK];
    for (int i = threadIdx.x; i < NBUCK; i += 256) lh[i] = 0;
    __syncthreads();
#pragma unroll
    for (int k = 0; k < 4; ++k) {
        int q = blockIdx.x * 1024 + k * 256 + threadIdx.x;  // int4 index, coalesced
        if (q < N_E4) {
            int4 d4 = ((const int4*)dst)[q];
            atomicAdd(&lh[d4.x >> BUCK_SHIFT], 1);
            atomicAdd(&lh[d4.y >> BUCK_SHIFT], 1);
            atomicAdd(&lh[d4.z >> BUCK_SHIFT], 1);
            atomicAdd(&lh[d4.w >> BUCK_SHIFT], 1);
        }
    }
    __syncthreads();
    for (int i = threadIdx.x; i < NBUCK; i += 256)
        hist[i * NBA + blockIdx.x] = lh[i];   // bucket-major layout for the scan
}

// ---- A2a: hierarchical scan pass 1 over hist (in-place) + block sums ----
__global__ void hist_scan1_kernel(int* __restrict__ hist, int* __restrict__ hbs) {
    __shared__ int lds[256];
    int base = blockIdx.x * 1024;
    int vals[4];
    int tsum = 0;
#pragma unroll
    for (int k = 0; k < 4; ++k) {
        int i = base + threadIdx.x * 4 + k;
        vals[k] = (i < HTOT) ? hist[i] : 0;
        tsum += vals[k];
    }
    lds[threadIdx.x] = tsum;
    __syncthreads();
    for (int off = 1; off < 256; off <<= 1) {
        int v = (threadIdx.x >= (unsigned)off) ? lds[threadIdx.x - off] : 0;
        __syncthreads();
        lds[threadIdx.x] += v;
        __syncthreads();
    }
    int run = lds[threadIdx.x] - tsum;      // local exclusive base
    if (threadIdx.x == 255) hbs[blockIdx.x] = lds[255];
    #pragma unroll
    for (int k = 0; k < 4; ++k) {
        int i = base + threadIdx.x * 4 + k;
        if (i < HTOT) hist[i] = run;        // in-place: own entries only
        run += vals[k];
    }
}

// ---- A2b: exclusive scan of the 240 hist block sums (single 256-thread block) ----
// Consumers (A3, B) add hbs[idx>>10] at read time -> no third pass.
__global__ void hist_scan2_kernel(int* __restrict__ hbs) {
    __shared__ int lds[256];
    int v = (threadIdx.x < (unsigned)NBH) ? hbs[threadIdx.x] : 0;
    lds[threadIdx.x] = v;
    __syncthreads();
    for (int off = 1; off < 256; off <<= 1) {
        int t = (threadIdx.x >= (unsigned)off) ? lds[threadIdx.x - off] : 0;
        __syncthreads();
        lds[threadIdx.x] += t;
        __syncthreads();
    }
    if (threadIdx.x < (unsigned)NBH) hbs[threadIdx.x] = lds[threadIdx.x] - v;
}

// ---- A3: scatter edges into ONE bucket-contiguous packed array (LDS cursors).
// packed = src | ((dst & 127) << 17): src < 2^17, local-dst 7 bits.
// (R10 showed sorted output buys nothing -> keep the simple low-VGPR version.) ----
__global__ void bucket_scatter_kernel(const int* __restrict__ src, const int* __restrict__ dst,
                                      const int* __restrict__ hist, const int* __restrict__ hbs,
                                      int* __restrict__ bedge) {
    __shared__ int cur[NBUCK];
    for (int i = threadIdx.x; i < NBUCK; i += 256) {
        int idx = i * NBA + blockIdx.x;
        cur[i] = hist[idx] + hbs[idx >> 10];
    }
    __syncthreads();
#pragma unroll
    for (int k = 0; k < 4; ++k) {
        int q = blockIdx.x * 1024 + k * 256 + threadIdx.x;
        if (q < N_E4) {
            int4 d4 = ((const int4*)dst)[q];
            int4 s4 = ((const int4*)src)[q];
            int p;
            p = atomicAdd(&cur[d4.x >> BUCK_SHIFT], 1);
            bedge[p] = s4.x | ((d4.x & (BUCK_NODES - 1)) << 17);
            p = atomicAdd(&cur[d4.y >> BUCK_SHIFT], 1);
            bedge[p] = s4.y | ((d4.y & (BUCK_NODES - 1)) << 17);
            p = atomicAdd(&cur[d4.z >> BUCK_SHIFT], 1);
            bedge[p] = s4.z | ((d4.z & (BUCK_NODES - 1)) << 17);
            p = atomicAdd(&cur[d4.w >> BUCK_SHIFT], 1);
            bedge[p] = s4.w | ((d4.w & (BUCK_NODES - 1)) << 17);
        }
    }
}

// ---- B: fused rank + row_start + norm + CSR fill + y0 (one block per bucket).
// 782 blocks (~3/CU) vs the old 196 (<1/CU): occupancy was the build bottleneck.
// Bucket b owns nodes [128b, 128b+128): deg sits in LDS -> dinv/rdinv/y0 local. ----
__global__ void bucket_build_kernel(const int* __restrict__ hist, const int* __restrict__ hbs,
                                    const int* __restrict__ bedge, const float* __restrict__ emb,
                                    int* __restrict__ col, int* __restrict__ row_start,
                                    float* __restrict__ dinv, float* __restrict__ rdinv,
                                    f16* __restrict__ y0) {
    __shared__ int lh[BUCK_NODES];
    __shared__ int sc[256];
    __shared__ int cur[BUCK_NODES];
    int k = blockIdx.x;
    int tid = threadIdx.x;
    int i0 = k * NBA;
    int beg = hist[i0] + hbs[i0 >> 10];
    int end;
    if (k + 1 < NBUCK) {
        int i1 = (k + 1) * NBA;
        end = hist[i1] + hbs[i1 >> 10];
    } else {
        end = N_EDGES;
    }
    if (tid < BUCK_NODES) lh[tid] = 0;
    __syncthreads();
    // pass 1: per-node counts
    for (int i = beg + tid; i < end; i += 256)
        atomicAdd(&lh[((unsigned)bedge[i]) >> 17], 1);
    __syncthreads();
    // exclusive scan of 128 bins (256-wide scan; entries >=128 are zero padding)
    int own = (tid < BUCK_NODES) ? lh[tid] : 0;
    sc[tid] = own;
    __syncthreads();
    for (int off = 1; off < 256; off <<= 1) {
        int v = (tid >= off) ? sc[tid - off] : 0;
        __syncthreads();
        sc[tid] += v;
        __syncthreads();
    }
    if (tid < BUCK_NODES) cur[tid] = sc[tid] - own;
    __syncthreads();
    // row_start + norms (node==N_NODES cap falls out naturally in bucket 781:
    // cur[32] there == all bucket edges -> beg+cur == N_EDGES)
    if (tid < BUCK_NODES) {
        int node = k * BUCK_NODES + tid;
        if (node <= N_NODES) {
            row_start[node] = beg + cur[tid];
            if (node < N_NODES) {
                int d = lh[tid];
                float fd = (float)d;
                dinv[node]  = (d > 0) ? rsqrtf(fd) : 0.0f;
                rdinv[node] = (d > 0) ? sqrtf(fd) : 0.0f;
            }
        }
    }
    __syncthreads();   // row_start reads of cur[] complete before fill mutates it
    // pass 2: fill col (bucket-local window -> L2-resident)
    for (int i = beg + tid; i < end; i += 256) {
        unsigned pe = (unsigned)bedge[i];
        int r = atomicAdd(&cur[pe >> 17], 1);
        col[beg + r] = (int)(pe & 0x1FFFFu);
    }
    // y0 for this bucket's 128 nodes: dv recomputed from lh (not mutated after pass 1)
    int nbase = k * BUCK_NODES;
#pragma unroll
    for (int it = 0; it < (BUCK_NODES * 16) / 256; ++it) {
        int i = it * 256 + tid;
        int node = nbase + (i >> 4);
        if (node < N_NODES) {
            float dd = (float)lh[i >> 4];
            float dv = (dd > 0.0f) ? rsqrtf(dd) : 0.0f;
            int quad = i & 15;
            float4 v = ((const float4*)emb)[(size_t)node * 16 + quad];
            f16 h[4] = {(f16)(v.x * dv), (f16)(v.y * dv), (f16)(v.z * dv), (f16)(v.w * dv)};
            ((u64*)y0)[(size_t)node * 16 + quad] = *(const u64*)h;
        }
    }
}

// ---- propagation: one wave per destination row, two slots, 8-deep MLP ----
// (R3/R6/R10-proven structure: 52 us FINAL. 8 independent loads issued before
// any consume buys the latency hiding -- R8's predicated unroll regressed.)
template <bool FINAL>
__global__ void gather_kernel(const int* __restrict__ row_start, const int* __restrict__ col,
                              const float* __restrict__ dinv, const float* __restrict__ rdinv,
                              const f16* __restrict__ yin, f16* __restrict__ yout,
                              const float* __restrict__ emb,
                              const f16* __restrict__ y1, const f16* __restrict__ y2,
                              float* __restrict__ out) {
    unsigned int gid = blockIdx.x * blockDim.x + threadIdx.x;
    unsigned int row = gid >> 6;       // wave-uniform
    int lane = (int)(gid & 63u);
    int s = lane >> 5;   // edge slot 0/1
    int j = lane & 31;   // dim pair: dims 2j, 2j+1
    if (row >= N_NODES) return;        // wave-uniform exit
    int beg = row_start[row];
    int end = row_start[row + 1];
    const f16* yj = yin + 2 * j;       // lane-fixed dim offset
    float accx = 0.0f, accy = 0.0f;
    for (int cb = beg; cb < end; cb += 64) {   // uniform bounds
        int idx = cb + lane;
        int ci = 0;
        if (idx < end) ci = col[idx];
        int n = end - cb;
        if (n > 64) n = 64;            // uniform
        int kk = 0;
        for (; kk + 8 <= n; kk += 8) { // 4 edges per slot: 8 gathers in flight/wave
            int c0 = __shfl(ci, kk + s);
            int c1 = __shfl(ci, kk + s + 2);
            int c2 = __shfl(ci, kk + s + 4);
            int c3 = __shfl(ci, kk + s + 6);
            unsigned u0 = *(const unsigned*)(yj + (unsigned)c0 * EMB);
            unsigned u1 = *(const unsigned*)(yj + (unsigned)c1 * EMB);
            unsigned u2 = *(const unsigned*)(yj + (unsigned)c2 * EMB);
            unsigned u3 = *(const unsigned*)(yj + (unsigned)c3 * EMB);
            f16x2 h0 = __builtin_bit_cast(f16x2, u0);
            f16x2 h1 = __builtin_bit_cast(f16x2, u1);
            f16x2 h2 = __builtin_bit_cast(f16x2, u2);
            f16x2 h3 = __builtin_bit_cast(f16x2, u3);
            accx += (float)h0.x + (float)h1.x + (float)h2.x + (float)h3.x;
            accy += (float)h0.y + (float)h1.y + (float)h2.y + (float)h3.y;
        }
        if (kk + 4 <= n) {             // uniform
            int c0 = __shfl(ci, kk + s);
            int c1 = __shfl(ci, kk + s + 2);
            unsigned u0 = *(const unsigned*)(yj + (unsigned)c0 * EMB);
            unsigned u1 = *(const unsigned*)(yj + (unsigned)c1 * EMB);
            f16x2 h0 = __builtin_bit_cast(f16x2, u0);
            f16x2 h1 = __builtin_bit_cast(f16x2, u1);
            accx += (float)h0.x + (float)h1.x;
            accy += (float)h0.y + (float)h1.y;
            kk += 4;
        }
        for (; kk < n; ++kk) {         // <=3 edges; shfl converged, acc predicated
            int c = __shfl(ci, kk);
            if (s == (kk & 1)) {
                unsigned u = *(const unsigned*)(yj + (unsigned)c * EMB);
                f16x2 h = __builtin_bit_cast(f16x2, u);
                accx += (float)h.x;
                accy += (float)h.y;
            }
        }
    }
    // merge the two edge slots (converged)
    accx += __shfl_xor(accx, 32);
    accy += __shfl_xor(accy, 32);
    if (s == 0) {
        float dv = dinv[row];
        unsigned int o = row * EMB + 2 * (unsigned)j;
        if (!FINAL) {
            float sc = dv * dv;
            f16x2 h;
            h.x = (f16)(accx * sc);
            h.y = (f16)(accy * sc);
            *(unsigned*)(yout + o) = __builtin_bit_cast(unsigned, h);  // cached: re-read next layer
        } else {
            float rv = rdinv[row];
            float2 e2 = *(const float2*)(emb + o);
            f16x2 a = __builtin_bit_cast(f16x2, *(const unsigned*)(y1 + o));
            f16x2 b = __builtin_bit_cast(f16x2, *(const unsigned*)(y2 + o));
            float rx = 0.25f * (e2.x + rv * ((float)a.x + (float)b.x) + dv * accx);
            float ry = 0.25f * (e2.y + rv * ((float)a.y + (float)b.y) + dv * accy);
            __builtin_nontemporal_store(rx, out + o);      // out is never re-read
            __builtin_nontemporal_store(ry, out + o + 1);
        }
    }
}

extern "C" void kernel_launch(void* const* d_in, const int* in_sizes, int n_in,
                              void* d_out, int out_size, void* d_ws, size_t ws_size,
                              hipStream_t stream) {
    const int*   edge = (const int*)d_in[0];   // (2, N_EDGES) row-major
    const int*   src  = edge;
    const int*   dst  = edge + N_EDGES;
    const float* emb  = (const float*)d_in[1]; // (N_NODES, 64) fp32
    float*       out  = (float*)d_out;

    // workspace carve (16B-aligned offsets)
    char* ws = (char*)d_ws;
    size_t off = 0;
    int* row_start = (int*)(ws + off); off += 400016;
    int* hbs       = (int*)(ws + off); off += 1024;  // hist-scan block sums (240)
    float* dinv    = (float*)(ws + off); off += 400000;
    float* rdinv   = (float*)(ws + off); off += 400000;
    int* hist      = (int*)(ws + off); off += (size_t)HTOT * 4 + 16;        // 979 KB
    int* col       = (int*)(ws + off); off += (size_t)N_EDGES * 4;          // 5.12 MB
    f16* y0        = (f16*)(ws + off); off += (size_t)N_NODES * EMB * 2;    // 12.8 MB
    f16* y1        = (f16*)(ws + off); off += (size_t)N_NODES * EMB * 2;    // 12.8 MB
    f16* y2        = (f16*)(ws + off); off += (size_t)N_NODES * EMB * 2;    // 12.8 MB

    // packed edge array aliases y1: dead before layer-1 gather writes y1.
    int* bedge = (int*)y1;                       // 5.12 MB

    // ---- CSR build via bucketed counting sort: zero global atomics, 5 dispatches ----
    bucket_hist_kernel<<<NBA, 256, 0, stream>>>(dst, hist);
    hist_scan1_kernel<<<NBH, 256, 0, stream>>>(hist, hbs);
    hist_scan2_kernel<<<1, 256, 0, stream>>>(hbs);
    bucket_scatter_kernel<<<NBA, 256, 0, stream>>>(src, dst, hist, hbs, bedge);
    bucket_build_kernel<<<NBUCK, 256, 0, stream>>>(hist, hbs, bedge, emb, col,
                                                   row_start, dinv, rdinv, y0);

    // ---- 3 propagation layers (pure y-sums), final fuses the 1/4-sum ----
    const unsigned int gthreads = (unsigned int)N_NODES * EMB;
    const int gblocks = (int)((gthreads + 255) / 256);
    gather_kernel<false><<<gblocks, 256, 0, stream>>>(row_start, col, dinv, rdinv,
                                                      y0, y1, emb, y1, y2, out);
    gather_kernel<false><<<gblocks, 256, 0, stream>>>(row_start, col, dinv, rdinv,
                                                      y1, y2, emb, y1, y2, out);
    gather_kernel<true><<<gblocks, 256, 0, stream>>>(row_start, col, dinv, rdinv,
                                                     y2, (f16*)0, emb, y1, y2, out);
}